// Round 4
// baseline (508.061 us; speedup 1.0000x reference)
//
#include <hip/hip_runtime.h>
#include <math.h>

#define NB 32          // MAX_NODES
#define BATCH 16384
#define MPB 8          // matrices per block
#define TPB (MPB * 32) // 256 threads, 4 waves

// ws layout (16 B, zeroed by hipMemsetAsync): [0]=bce_sum [1]=mask_sum [2]=phys_sum [3]=unused

__device__ __forceinline__ float groupReduceSum(float v) {
    // sum within each 32-lane group (xor masks <=16 stay in-group)
    v += __shfl_xor(v, 1, 64);
    v += __shfl_xor(v, 2, 64);
    v += __shfl_xor(v, 4, 64);
    v += __shfl_xor(v, 8, 64);
    v += __shfl_xor(v, 16, 64);
    return v;
}

// 8 matrices per 256-thread block (each 32-lane group owns one matrix).
// Phase 3 (Householder) is register/shuffle-only, verbatim the round-3
// verified version. Round-4 changes (spill elimination — round-3 post-mortem
// showed VGPR_Count=60 vs >=128 live floats => compiler spilling):
//   (1) __launch_bounds__(TPB,2): VGPR cap 256 so the allocator can't clamp
//       to the 8-waves boundary and spill.
//   (2) d[]/e2[] (64 regs) moved to LDS, written once and barrier-protected
//       (__syncthreads) before Sturm reads them via a VOLATILE pointer
//       (prevents re-hoisting into registers / re-spilling). Uniform address
//       per 32-lane group -> broadcast read, 2-way bank alias only (free).
// Target: peak live state ~a[32]+xv[32]+temps < 128 VGPR -> 4 waves/SIMD.
__global__ __launch_bounds__(TPB, 2)
void lap_main(const float* __restrict__ predA, const float* __restrict__ targA,
              const float* __restrict__ nmask, float* __restrict__ out,
              float* __restrict__ ws)
{
    __shared__ float sde[MPB][NB][2];   // [i][0]=d_i, [i][1]=e2_{i-1} (slot 0 unused)

    const int t    = threadIdx.x;           // 0..255
    const int j    = t & 31;                // row index within matrix
    const int mm   = t >> 5;                // matrix within block (0..7)
    const int half = mm & 1;                // 32-lane half within the wave
    const int b    = blockIdx.x * MPB + mm; // batch index
    const size_t base = (size_t)b * (NB * NB);

    // ---- phase 1: per-lane row loads, BCE partials, pred row -> a[] ----
    const float  mr  = nmask[(size_t)blockIdx.x * (MPB * NB) + t];
    const float4* pr4 = (const float4*)(predA + base + (size_t)j * NB);
    const float4* tr4 = (const float4*)(targA + base + (size_t)j * NB);
    const float4* nm4 = (const float4*)(nmask + (size_t)b * NB);

    float a[NB];
    float accB = 0.f, accM = 0.f;
    #pragma unroll
    for (int q = 0; q < 8; ++q) {
        const float4 p  = pr4[q];
        const float4 tg = tr4[q];
        const float4 mc = nm4[q];
        const float bx = -(tg.x * __logf(p.x) + (1.f - tg.x) * __logf(1.f - p.x));
        const float by = -(tg.y * __logf(p.y) + (1.f - tg.y) * __logf(1.f - p.y));
        const float bz = -(tg.z * __logf(p.z) + (1.f - tg.z) * __logf(1.f - p.z));
        const float bw = -(tg.w * __logf(p.w) + (1.f - tg.w) * __logf(1.f - p.w));
        accB += mr * (mc.x * bx + mc.y * by + mc.z * bz + mc.w * bw);
        accM += mr * (mc.x + mc.y + mc.z + mc.w);
        a[4*q+0] = p.x; a[4*q+1] = p.y; a[4*q+2] = p.z; a[4*q+3] = p.w;
    }
    accB = groupReduceSum(accB); accB += __shfl_xor(accB, 32, 64);
    accM = groupReduceSum(accM); accM += __shfl_xor(accM, 32, 64);
    if ((t & 63) == 0) { atomicAdd(ws + 0, accB); atomicAdd(ws + 1, accM); }

    // ---- phase 2: M = (L+L^T)/2 in place; col coalesced from global ----
    float dsum = 0.f, pdiag = 0.f;
    #pragma unroll
    for (int i = 0; i < NB; ++i) {
        dsum += a[i];
        pdiag = (i == j) ? a[i] : pdiag;
    }
    const float jitter = 1e-5f + (9e-5f / 31.f) * (float)j;
    const float dval = dsum + jitter - pdiag;
    #pragma unroll
    for (int i = 0; i < NB; ++i) {
        const float cv = predA[base + (size_t)i * NB + j];  // coalesced across lanes
        const float s  = -0.5f * (a[i] + cv);
        a[i] = (i == j) ? dval : s;
    }

    // ---- phase 3: Householder tridiagonalization (round-3 verified) ----
    float xv[NB];
    #pragma unroll
    for (int i = 0; i < NB; ++i) xv[i] = 0.f;
    float colk = a[0];                      // lane j holds A[j][k] for current k
    for (int k = 0; k < NB - 2; ++k) {
        const float sg = groupReduceSum((j > k) ? colk * colk : 0.f);
        const float x1 = __shfl(colk, k + 1, 32);
        const float al = (x1 >= 0.f) ? -sqrtf(sg) : sqrtf(sg);
        const float denom = sg - al * x1;
        const float beta  = (denom > 1e-30f) ? __builtin_amdgcn_rcpf(denom) : 0.f;
        const float vj = (j > k) ? (colk - ((j == k + 1) ? al : 0.f)) : 0.f;

        // broadcast v (all lanes active) + dot = a_row . v, skipping dead chunks
        float ac0 = 0.f, ac1 = 0.f, ac2 = 0.f, ac3 = 0.f;
        #pragma unroll
        for (int q = 0; q < 8; ++q) {
            if (4*q + 3 >= k) {
                #pragma unroll
                for (int u = 0; u < 4; ++u) {
                    const int i = 4*q + u;
                    float cb = __shfl(colk, i, 32);
                    cb = (i == k + 1) ? (x1 - al) : cb;   // uniform cond
                    xv[i] = (i > k) ? cb : 0.f;           // uniform cond
                }
                ac0 += a[4*q+0] * xv[4*q+0];
                ac1 += a[4*q+1] * xv[4*q+1];
                ac2 += a[4*q+2] * xv[4*q+2];
                ac3 += a[4*q+3] * xv[4*q+3];
            }
        }
        const float dot = (ac0 + ac1) + (ac2 + ac3);
        const float pj  = beta * dot;
        const float pjm = (j >= k) ? pj : 0.f;     // frozen lanes contribute 0
        const float K   = groupReduceSum(vj * pjm); // all lanes active
        const float c   = 0.5f * beta * K;
        const float s2  = pjm - 2.f * c * vj;
        const float nvj = -vj, ns2 = -s2;

        // rank-2 update under HARD row guard: frozen rows provably untouched
        float ncol = colk;
        if (j >= k) {
            #pragma unroll
            for (int q = 0; q < 8; ++q) {
                if (4*q + 3 >= k) {
                    #pragma unroll
                    for (int u = 0; u < 4; ++u) {
                        const int i = 4*q + u;
                        if (i >= k) {                       // uniform cond
                            const float pv = __shfl(pj, i, 32);
                            float av = a[i];
                            av = fmaf(nvj, pv, av);
                            av = fmaf(ns2, xv[i], av);
                            a[i] = av;
                            ncol = (i == k + 1) ? av : ncol; // carry col k+1
                        }
                    }
                }
            }
        }
        colk = ncol;
    }

    // ---- extraction: lane j keeps d_j = A[j][j], e_{j-1} = A[j][j-1] ----
    // (rows are final by the hard guard). cndmask captures, no shuffles.
    float dloc = 0.f, eloc = 0.f;
    #pragma unroll
    for (int i = 0; i < NB; ++i) {
        dloc = (i == j)     ? a[i] : dloc;
        eloc = (i == j - 1) ? a[i] : eloc;   // lane 0 keeps 0
    }

    // Gershgorin bounds via 10-shuffle min/max reduce
    const float aej = fabsf(eloc);                       // |e_{j-1}|
    const float aer = __shfl(aej, (j + 1) & 31, 32);     // |e_j| (lane31 -> lane0 = 0)
    float mlo = dloc - (aej + aer);
    float mhi = dloc + (aej + aer);
    #pragma unroll
    for (int msk = 1; msk <= 16; msk <<= 1) {
        mlo = fminf(mlo, __shfl_xor(mlo, msk, 64));
        mhi = fmaxf(mhi, __shfl_xor(mhi, msk, 64));
    }
    float lo = mlo, hi = mhi;

    // publish d/e2 to LDS; barrier before the broadcast reads
    *(float2*)&sde[mm][j][0] = make_float2(dloc, eloc * eloc);
    __syncthreads();

    // ---- phase 4: Sturm multisection (32 sigmas/round, 3 rounds) ----
    // volatile: force ds_read each use so d/e2 never re-materialize in regs
    volatile const float* de = &sde[mm][0][0];
    for (int round = 0; round < 3; ++round) {
        const float step = (hi - lo) * (1.f / 33.f);
        const float sig = lo + step * (float)(j + 1);
        float q = de[0] - sig;
        int cnt = (q < 0.f);
        #pragma unroll
        for (int i = 1; i < NB; ++i) {
            const float di = de[2*i];
            const float ee = de[2*i + 1];
            if (fabsf(q) < 1e-20f) q = (q < 0.f) ? -1e-20f : 1e-20f;
            q = (di - sig) - ee * __builtin_amdgcn_rcpf(q);
            cnt += (q < 0.f);
        }
        const unsigned long long bal = __ballot(cnt >= 2);
        const unsigned int bits = (unsigned int)(bal >> (half * 32));
        const int jstar = (bits == 0u) ? 32 : __builtin_ctz(bits);
        const float nlo = lo + step * (float)jstar;
        const float nhi = lo + step * (float)(jstar + 1);
        lo = nlo; hi = nhi;
    }
    const float lam2 = 0.5f * (lo + hi);

    if (j == 0) out[2 + b] = lam2;
    const float ph = fmaxf(0.1f - lam2, 0.f);
    const float ph0 = __shfl(ph, 0, 64);
    const float ph1 = __shfl(ph, 32, 64);
    if ((t & 63) == 0) atomicAdd(ws + 2, ph0 + ph1);   // one add per wave (2 matrices)
}

__global__ __launch_bounds__(64)
void lap_final(float* __restrict__ out, const float* __restrict__ ws) {
    if (threadIdx.x == 0) {
        out[0] = ws[0] / fmaxf(ws[1], 1.f);
        out[1] = ws[2] * (1.f / (float)BATCH);
    }
}

extern "C" void kernel_launch(void* const* d_in, const int* in_sizes, int n_in,
                              void* d_out, int out_size, void* d_ws, size_t ws_size,
                              hipStream_t stream) {
    const float* pred = (const float*)d_in[0];
    const float* targ = (const float*)d_in[1];
    const float* nm   = (const float*)d_in[2];
    float* out = (float*)d_out;
    float* ws  = (float*)d_ws;

    (void)hipMemsetAsync(d_ws, 0, 16, stream);
    hipLaunchKernelGGL(lap_main, dim3(BATCH / MPB), dim3(TPB), 0, stream,
                       pred, targ, nm, out, ws);
    hipLaunchKernelGGL(lap_final, dim3(1), dim3(64), 0, stream, out, ws);
}

// Round 5
// 466.870 us; speedup vs baseline: 1.0882x; 1.0882x over previous
//
#include <hip/hip_runtime.h>
#include <math.h>

#define NB 32          // MAX_NODES
#define BATCH 16384
#define MPB 8          // matrices per block
#define TPB (MPB * 32) // 256 threads, 4 waves

// ws layout (16 B, zeroed by hipMemsetAsync): [0]=bce_sum [1]=mask_sum [2]=phys_sum [3]=unused

// ---- DPP cross-lane helpers (VALU pipe, not DS pipe) ----
// row_ror:N rotates within each 16-lane row; rotation-butterfly over
// {1,2,4,8} gives a full 16-lane reduce-to-all (circulant reduction).
template<int CTRL>
__device__ __forceinline__ float dpp_add(float v) {
    const int s = __float_as_int(v);
    const int r = __builtin_amdgcn_update_dpp(s, s, CTRL, 0xF, 0xF, false);
    return v + __int_as_float(r);
}
template<int CTRL>
__device__ __forceinline__ float dpp_min(float v) {
    const int s = __float_as_int(v);
    const int r = __builtin_amdgcn_update_dpp(s, s, CTRL, 0xF, 0xF, false);
    return fminf(v, __int_as_float(r));
}
template<int CTRL>
__device__ __forceinline__ float dpp_max(float v) {
    const int s = __float_as_int(v);
    const int r = __builtin_amdgcn_update_dpp(s, s, CTRL, 0xF, 0xF, false);
    return fmaxf(v, __int_as_float(r));
}
// sum over each 32-lane group, result in all lanes: 4 DPP adds + 1 swizzle
__device__ __forceinline__ float grp32_sum(float v) {
    v = dpp_add<0x121>(v);   // row_ror:1
    v = dpp_add<0x122>(v);   // row_ror:2
    v = dpp_add<0x124>(v);   // row_ror:4
    v = dpp_add<0x128>(v);   // row_ror:8  -> 16-row total in every lane
    v += __shfl_xor(v, 16, 64);
    return v;
}
__device__ __forceinline__ float grp32_min(float v) {
    v = dpp_min<0x121>(v); v = dpp_min<0x122>(v);
    v = dpp_min<0x124>(v); v = dpp_min<0x128>(v);
    return fminf(v, __shfl_xor(v, 16, 64));
}
__device__ __forceinline__ float grp32_max(float v) {
    v = dpp_max<0x121>(v); v = dpp_max<0x122>(v);
    v = dpp_max<0x124>(v); v = dpp_max<0x128>(v);
    return fmaxf(v, __shfl_xor(v, 16, 64));
}

// 8 matrices per 256-thread block (each 32-lane group owns one matrix).
// Round-5 change (R3/R4 post-mortem: time invariant at ~403us across 2x
// instruction-count change => dependent DS-pipe chain is the limiter):
//   (1) shuffle reductions -> DPP row_ror reductions (VALU pipe): 5 DS -> 1 DS
//   (2) v/p broadcasts -> pre-masked LDS arrays, written 1x b32 per lane and
//       read back as uniform-address ds_read_b128 (free broadcast): ~40
//       bpermute/iter -> ~18 DS/iter. Double-buffered by k parity (WAR safe).
//       HARD row guard j>=k kept verbatim (round-2 lesson) -> frozen rows
//       provably untouched; masked LDS values are exact zeros into multiplies.
//   (3) Sturm d/e2: float2 loads + per-round asm memory clobber (loads hoist
//       off the rcp chain in-round, can't re-materialize across rounds).
__global__ __launch_bounds__(TPB, 2)
void lap_main(const float* __restrict__ predA, const float* __restrict__ targA,
              const float* __restrict__ nmask, float* __restrict__ out,
              float* __restrict__ ws)
{
    __shared__ float sv[2][MPB][NB];    // masked Householder v (0 for j<=k)
    __shared__ float sp[2][MPB][NB];    // masked p (0 for j<k)
    __shared__ float sde[MPB][NB][2];   // [i][0]=d_i, [i][1]=e2_{i-1}

    const int t    = threadIdx.x;           // 0..255
    const int j    = t & 31;                // row index within matrix
    const int mm   = t >> 5;                // matrix within block (0..7)
    const int half = mm & 1;                // 32-lane half within the wave
    const int b    = blockIdx.x * MPB + mm; // batch index
    const size_t base = (size_t)b * (NB * NB);

    // ---- phase 1: per-lane row loads, BCE partials, pred row -> a[] ----
    const float  mr  = nmask[(size_t)blockIdx.x * (MPB * NB) + t];
    const float4* pr4 = (const float4*)(predA + base + (size_t)j * NB);
    const float4* tr4 = (const float4*)(targA + base + (size_t)j * NB);
    const float4* nm4 = (const float4*)(nmask + (size_t)b * NB);

    float a[NB];
    float accB = 0.f, accM = 0.f;
    #pragma unroll
    for (int q = 0; q < 8; ++q) {
        const float4 p  = pr4[q];
        const float4 tg = tr4[q];
        const float4 mc = nm4[q];
        const float bx = -(tg.x * __logf(p.x) + (1.f - tg.x) * __logf(1.f - p.x));
        const float by = -(tg.y * __logf(p.y) + (1.f - tg.y) * __logf(1.f - p.y));
        const float bz = -(tg.z * __logf(p.z) + (1.f - tg.z) * __logf(1.f - p.z));
        const float bw = -(tg.w * __logf(p.w) + (1.f - tg.w) * __logf(1.f - p.w));
        accB += mr * (mc.x * bx + mc.y * by + mc.z * bz + mc.w * bw);
        accM += mr * (mc.x + mc.y + mc.z + mc.w);
        a[4*q+0] = p.x; a[4*q+1] = p.y; a[4*q+2] = p.z; a[4*q+3] = p.w;
    }
    accB = grp32_sum(accB); accB += __shfl_xor(accB, 32, 64);
    accM = grp32_sum(accM); accM += __shfl_xor(accM, 32, 64);
    if ((t & 63) == 0) { atomicAdd(ws + 0, accB); atomicAdd(ws + 1, accM); }

    // ---- phase 2: M = (L+L^T)/2 in place; col coalesced from global ----
    float dsum = 0.f, pdiag = 0.f;
    #pragma unroll
    for (int i = 0; i < NB; ++i) {
        dsum += a[i];
        pdiag = (i == j) ? a[i] : pdiag;
    }
    const float jitter = 1e-5f + (9e-5f / 31.f) * (float)j;
    const float dval = dsum + jitter - pdiag;
    #pragma unroll
    for (int i = 0; i < NB; ++i) {
        const float cv = predA[base + (size_t)i * NB + j];  // coalesced across lanes
        const float s  = -0.5f * (a[i] + cv);
        a[i] = (i == j) ? dval : s;
    }

    // ---- phase 3: Householder, rolled; LDS b128 broadcasts + DPP reduces ----
    float xv[NB];
    float colk = a[0];                      // lane j holds A[j][k] for current k
    for (int k = 0; k < NB - 2; ++k) {
        const int pk = k & 1;
        const float sg = grp32_sum((j > k) ? colk * colk : 0.f);
        const float x1 = __shfl(colk, k + 1, 32);
        const float al = (x1 >= 0.f) ? -sqrtf(sg) : sqrtf(sg);
        const float denom = sg - al * x1;
        const float beta  = (denom > 1e-30f) ? __builtin_amdgcn_rcpf(denom) : 0.f;
        // vj includes the (j==k+1) -al fixup -> LDS v needs no read-side fixup
        const float vj = (j > k) ? (colk - ((j == k + 1) ? al : 0.f)) : 0.f;
        sv[pk][mm][j] = vj;                 // pre-masked: exact 0 for j<=k

        // dot = a_row . v via uniform-address b128 broadcast reads
        const float4* xv4 = (const float4*)&sv[pk][mm][0];
        float ac0 = 0.f, ac1 = 0.f, ac2 = 0.f, ac3 = 0.f;
        #pragma unroll
        for (int q = 0; q < 8; ++q) {
            if (4*q + 3 >= k) {             // wave-uniform chunk skip
                const float4 x = xv4[q];
                xv[4*q+0] = x.x; xv[4*q+1] = x.y; xv[4*q+2] = x.z; xv[4*q+3] = x.w;
                ac0 += a[4*q+0] * x.x;
                ac1 += a[4*q+1] * x.y;
                ac2 += a[4*q+2] * x.z;
                ac3 += a[4*q+3] * x.w;
            }
        }
        const float dot = (ac0 + ac1) + (ac2 + ac3);
        const float pj  = beta * dot;
        const float pjm = (j >= k) ? pj : 0.f;     // frozen lanes publish 0
        sp[pk][mm][j] = pjm;
        const float K   = grp32_sum(vj * pjm);
        const float c   = 0.5f * beta * K;
        const float s2  = pjm - 2.f * c * vj;
        const float nvj = -vj, ns2 = -s2;

        // rank-2 update under HARD row guard: frozen rows provably untouched.
        // pv from LDS equals shfl(pj,i) at every consumed site (i>=k).
        const float4* pv4 = (const float4*)&sp[pk][mm][0];
        float ncol = colk;
        if (j >= k) {
            #pragma unroll
            for (int q = 0; q < 8; ++q) {
                if (4*q + 3 >= k) {
                    const float4 p4 = pv4[q];
                    #pragma unroll
                    for (int u = 0; u < 4; ++u) {
                        const int i = 4*q + u;
                        if (i >= k) {                       // uniform cond
                            const float pv = (u == 0) ? p4.x : (u == 1) ? p4.y
                                           : (u == 2) ? p4.z : p4.w;
                            float av = a[i];
                            av = fmaf(nvj, pv, av);
                            av = fmaf(ns2, xv[i], av);
                            a[i] = av;
                            ncol = (i == k + 1) ? av : ncol; // carry col k+1
                        }
                    }
                }
            }
        }
        colk = ncol;
    }

    // ---- extraction: lane j keeps d_j = A[j][j], e_{j-1} = A[j][j-1] ----
    float dloc = 0.f, eloc = 0.f;
    #pragma unroll
    for (int i = 0; i < NB; ++i) {
        dloc = (i == j)     ? a[i] : dloc;
        eloc = (i == j - 1) ? a[i] : eloc;   // lane 0 keeps 0
    }

    // Gershgorin bounds via DPP min/max reduce
    const float aej = fabsf(eloc);                       // |e_{j-1}|
    const float aer = __shfl(aej, (j + 1) & 31, 32);     // |e_j| (lane31 -> 0)
    float lo = grp32_min(dloc - (aej + aer));
    float hi = grp32_max(dloc + (aej + aer));

    // publish d/e2 to LDS (in-wave producer/consumer, same ordering model
    // as sv/sp above)
    *(float2*)&sde[mm][j][0] = make_float2(dloc, eloc * eloc);

    // ---- phase 4: Sturm multisection (32 sigmas/round, 3 rounds) ----
    const float2* de2 = (const float2*)&sde[mm][0][0];
    for (int round = 0; round < 3; ++round) {
        asm volatile("" ::: "memory");   // force reload per round (no reg CSE)
        const float step = (hi - lo) * (1.f / 33.f);
        const float sig = lo + step * (float)(j + 1);
        const float2 d0 = de2[0];
        float q = d0.x - sig;
        int cnt = (q < 0.f);
        #pragma unroll
        for (int i = 1; i < NB; ++i) {
            const float2 di = de2[i];     // hoistable within the round
            if (fabsf(q) < 1e-20f) q = (q < 0.f) ? -1e-20f : 1e-20f;
            q = (di.x - sig) - di.y * __builtin_amdgcn_rcpf(q);
            cnt += (q < 0.f);
        }
        const unsigned long long bal = __ballot(cnt >= 2);
        const unsigned int bits = (unsigned int)(bal >> (half * 32));
        const int jstar = (bits == 0u) ? 32 : __builtin_ctz(bits);
        const float nlo = lo + step * (float)jstar;
        const float nhi = lo + step * (float)(jstar + 1);
        lo = nlo; hi = nhi;
    }
    const float lam2 = 0.5f * (lo + hi);

    if (j == 0) out[2 + b] = lam2;
    const float ph = fmaxf(0.1f - lam2, 0.f);
    const float ph0 = __shfl(ph, 0, 64);
    const float ph1 = __shfl(ph, 32, 64);
    if ((t & 63) == 0) atomicAdd(ws + 2, ph0 + ph1);   // one add per wave (2 matrices)
}

__global__ __launch_bounds__(64)
void lap_final(float* __restrict__ out, const float* __restrict__ ws) {
    if (threadIdx.x == 0) {
        out[0] = ws[0] / fmaxf(ws[1], 1.f);
        out[1] = ws[2] * (1.f / (float)BATCH);
    }
}

extern "C" void kernel_launch(void* const* d_in, const int* in_sizes, int n_in,
                              void* d_out, int out_size, void* d_ws, size_t ws_size,
                              hipStream_t stream) {
    const float* pred = (const float*)d_in[0];
    const float* targ = (const float*)d_in[1];
    const float* nm   = (const float*)d_in[2];
    float* out = (float*)d_out;
    float* ws  = (float*)d_ws;

    (void)hipMemsetAsync(d_ws, 0, 16, stream);
    hipLaunchKernelGGL(lap_main, dim3(BATCH / MPB), dim3(TPB), 0, stream,
                       pred, targ, nm, out, ws);
    hipLaunchKernelGGL(lap_final, dim3(1), dim3(64), 0, stream, out, ws);
}